// Round 1
// baseline (1005.847 us; speedup 1.0000x reference)
//
#include <hip/hip_runtime.h>

// Problem constants (from reference): B=32, IN=16, C=8192, U=32, K=16, 3 routing iters.
#define CC   8192
#define UU   32
#define KK   16
#define BB   32
#define INU  16
#define UK   512      // U*K
#define CPB  16       // channels per block (SMEM path): 512 blocks -> 2 blocks/CU -> 16 waves/CU
#define NBLK 512      // CC / CPB

typedef __attribute__((ext_vector_type(16))) float f32x16;

// -------------------------------------------------------------------------
// One-time x transpose: xT[c][b*16+i] = x[b][i][c].
// Makes per-channel x a contiguous 2KB row so fused_pass can stream it into
// SGPRs with s_load_dwordx16 (x is wave-uniform -> scalar pipe, not LDS).
// -------------------------------------------------------------------------
__global__ __launch_bounds__(256) void transpose_x(
    const float* __restrict__ x, float* __restrict__ xT)
{
    __shared__ float tile[64][65];
    const int bc = blockIdx.x & 127;           // 128 c-tiles of 64
    const int bb = blockIdx.x >> 7;            // 8 bi-tiles of 64 (B*IN = 512)
    const int c0 = bc * 64, bi0 = bb * 64;
    const int tx = threadIdx.x & 63, ty = threadIdx.x >> 6;  // 64 x 4
#pragma unroll
    for (int j = 0; j < 64; j += 4)
        tile[ty + j][tx] = x[(size_t)(bi0 + ty + j) * CC + (c0 + tx)];  // coalesced in c
    __syncthreads();
#pragma unroll
    for (int j = 0; j < 64; j += 4)                                      // coalesced in bi
        xT[(size_t)(c0 + ty + j) * (BB * INU) + (bi0 + tx)] = tile[tx][ty + j];
}

// -------------------------------------------------------------------------
// Fused routing pass (SMEM x delivery, zero LDS in the hot loop):
//   per c: u_hat[b,uk] = sum_i W[c,uk,i]*xT[c,b,i]
//          a[c,u]  = (1/B) sum_{b,k} u_hat * v_in
//          b_new   = b_io + a ; e = exp(b_new) ; b_io <- b_new
//          Z[u]   += e ;  S[b,uk] += e * u_hat
// x is wave-uniform per (c,b): one s_load_dwordx16 -> 16 SGPRs, consumed as
// the scalar operand of v_fma_f32. Depth-1 prefetch; tied "+s" waitcnt +
// sched_barrier(0) per rule #18 (register-only FMAs aren't ordered by
// "memory" clobbers).
// -------------------------------------------------------------------------
#define SBODY(XC, XN, B, NP)                                                  \
    asm volatile("s_load_dwordx16 %0, %1, 0" : "=s"(XN) : "s"(NP));           \
    {                                                                         \
        float h0 = w0.x * XC[0];                                              \
        float h1 = w0.z * XC[2];                                              \
        float h2 = w1.x * XC[4];                                              \
        float h3 = w1.z * XC[6];                                              \
        h0 = fmaf(w0.y, XC[1],  h0);  h1 = fmaf(w0.w, XC[3],  h1);            \
        h2 = fmaf(w1.y, XC[5],  h2);  h3 = fmaf(w1.w, XC[7],  h3);            \
        h0 = fmaf(w2.x, XC[8],  h0);  h1 = fmaf(w2.z, XC[10], h1);            \
        h2 = fmaf(w3.x, XC[12], h2);  h3 = fmaf(w3.z, XC[14], h3);            \
        h0 = fmaf(w2.y, XC[9],  h0);  h1 = fmaf(w2.w, XC[11], h1);            \
        h2 = fmaf(w3.y, XC[13], h2);  h3 = fmaf(w3.w, XC[15], h3);            \
        float hs = (h0 + h1) + (h2 + h3);                                     \
        uh[B] = hs;                                                           \
        ap = fmaf(hs, v[B], ap);                                              \
    }                                                                         \
    asm volatile("s_waitcnt lgkmcnt(0)" : "+s"(XN));                          \
    __builtin_amdgcn_sched_barrier(0);

__global__ __launch_bounds__(512, 4) void fused_pass(
    const float* __restrict__ W, const float* __restrict__ xT,
    const float* __restrict__ v_in, float* __restrict__ b_io,
    float* __restrict__ S, float* __restrict__ Z)
{
    const int t   = threadIdx.x;   // uk = u*16 + k
    const int bid = blockIdx.x;
    const int c0  = bid * CPB;
    const int u   = t >> 4;
    const int k   = t & 15;

    float v[BB], Sl[BB], uh[BB];
#pragma unroll
    for (int b = 0; b < BB; ++b) { v[b] = v_in[b * UK + t]; Sl[b] = 0.f; }
    float zloc = 0.f;

    // W row: 16 consecutive floats per (c, uk); wave reads 4KB contiguous -> the HBM stream.
    float4 w0, w1, w2, w3;
    {
        const float4* p = (const float4*)(W + ((size_t)c0 * UK + t) * INU);
        w0 = p[0]; w1 = p[1]; w2 = p[2]; w3 = p[3];
    }

    // Scalar x pipeline: prime with (cc=0, b=0).
    f32x16 xa, xb;
    {
        const float* p0 = xT + (size_t)c0 * (BB * INU);
        asm volatile("s_load_dwordx16 %0, %1, 0" : "=s"(xa) : "s"(p0));
        asm volatile("s_waitcnt lgkmcnt(0)" : "+s"(xa));
        __builtin_amdgcn_sched_barrier(0);
    }

    for (int cc = 0; cc < CPB; ++cc) {
        // Prefetch next c's W row (global/vmcnt; independent of the lgkm x chain).
        float4 n0, n1, n2, n3;
        const bool have_next = (cc + 1 < CPB);
        if (have_next) {
            const float4* p = (const float4*)(W + ((size_t)(c0 + cc + 1) * UK + t) * INU);
            n0 = p[0]; n1 = p[1]; n2 = p[2]; n3 = p[3];
        }

        const float* xrow  = xT + (size_t)(c0 + cc) * (BB * INU);
        const float* xnext = have_next ? (xrow + BB * INU) : xrow;  // clamp at block end

        float ap = 0.f;
#pragma unroll
        for (int b = 0; b < BB; b += 2) {
            const float* np0 = xrow + (size_t)(b + 1) * INU;
            SBODY(xa, xb, b, np0)
            const float* np1 = (b + 2 < BB) ? (xrow + (size_t)(b + 2) * INU) : xnext;
            SBODY(xb, xa, b + 1, np1)
        }

        // Reduce a over k: 16 lanes per u within the wave (t = u*16+k, k fast).
        ap += __shfl_xor(ap, 8);
        ap += __shfl_xor(ap, 4);
        ap += __shfl_xor(ap, 2);
        ap += __shfl_xor(ap, 1);

        const int c = c0 + cc;
        float bnew = b_io[c * UU + u] + ap * (1.0f / (float)BB);
        float e = __expf(bnew);
        zloc += e;
        if (k == 0) b_io[c * UU + u] = bnew;

#pragma unroll
        for (int b = 0; b < BB; ++b) Sl[b] = fmaf(e, uh[b], Sl[b]);

        if (have_next) { w0 = n0; w1 = n1; w2 = n2; w3 = n3; }
    }

    // Flush: 64 consecutive lanes -> consecutive addresses, coalesced atomics.
#pragma unroll
    for (int b = 0; b < BB; ++b) atomicAdd(S + b * UK + t, Sl[b]);
    if (k == 0) atomicAdd(Z + u, zloc);
}

// -------------------------------------------------------------------------
// Fallback pass (previous proven kernel, LDS-broadcast path) — used only if
// the workspace is too small for xT. 32 channels/block, grid 256.
// -------------------------------------------------------------------------
__global__ __launch_bounds__(512, 2) void fused_pass_lds(
    const float* __restrict__ x, const float* __restrict__ W,
    const float* __restrict__ v_in, float* __restrict__ b_io,
    float* __restrict__ S, float* __restrict__ Z)
{
    __shared__ float xs[16 * 516];

    const int t   = threadIdx.x;
    const int bid = blockIdx.x;
    const int c0  = bid * 32;
    const int u   = t >> 4;
    const int k   = t & 15;

    float v[BB], Sl[BB], uh[BB];
#pragma unroll
    for (int b = 0; b < BB; ++b) { v[b] = v_in[b * UK + t]; Sl[b] = 0.f; }
    float zloc = 0.f;

    float4 w0, w1, w2, w3;
    {
        const float4* p = (const float4*)(W + ((size_t)c0 * UK + t) * INU);
        w0 = p[0]; w1 = p[1]; w2 = p[2]; w3 = p[3];
    }

    for (int cc = 0; cc < 32; ++cc) {
        if ((cc & 15) == 0) {
            __syncthreads();
            const int cbase = c0 + (cc & ~15);
            for (int j = 0; j < 16; ++j) {
                int idx = j * 512 + t;
                int ccl = idx & 15;
                int bi  = idx >> 4;
                xs[ccl * 516 + bi] = x[bi * CC + cbase + ccl];
            }
            __syncthreads();
        }

        float4 n0, n1, n2, n3;
        const bool have_next = (cc + 1 < 32);
        if (have_next) {
            const float4* p = (const float4*)(W + ((size_t)(c0 + cc + 1) * UK + t) * INU);
            n0 = p[0]; n1 = p[1]; n2 = p[2]; n3 = p[3];
        }

        const float* xrow = &xs[(cc & 15) * 516];
        float ap = 0.f;
#pragma unroll
        for (int b = 0; b < BB; ++b) {
            const float4* xr = (const float4*)(xrow + b * INU);
            float4 x0 = xr[0], x1 = xr[1], x2 = xr[2], x3 = xr[3];
            float h;
            h = w0.x * x0.x;
            h = fmaf(w0.y, x0.y, h); h = fmaf(w0.z, x0.z, h); h = fmaf(w0.w, x0.w, h);
            h = fmaf(w1.x, x1.x, h); h = fmaf(w1.y, x1.y, h);
            h = fmaf(w1.z, x1.z, h); h = fmaf(w1.w, x1.w, h);
            h = fmaf(w2.x, x2.x, h); h = fmaf(w2.y, x2.y, h);
            h = fmaf(w2.z, x2.z, h); h = fmaf(w2.w, x2.w, h);
            h = fmaf(w3.x, x3.x, h); h = fmaf(w3.y, x3.y, h);
            h = fmaf(w3.z, x3.z, h); h = fmaf(w3.w, x3.w, h);
            uh[b] = h;
            ap = fmaf(h, v[b], ap);
        }

        ap += __shfl_xor(ap, 8);
        ap += __shfl_xor(ap, 4);
        ap += __shfl_xor(ap, 2);
        ap += __shfl_xor(ap, 1);

        const int c = c0 + cc;
        float bnew = b_io[c * UU + u] + ap * (1.0f / (float)BB);
        float e = __expf(bnew);
        zloc += e;
        if (k == 0) b_io[c * UU + u] = bnew;

#pragma unroll
        for (int b = 0; b < BB; ++b) Sl[b] = fmaf(e, uh[b], Sl[b]);

        if (have_next) { w0 = n0; w1 = n1; w2 = n2; w3 = n3; }
    }

#pragma unroll
    for (int b = 0; b < BB; ++b) atomicAdd(S + b * UK + t, Sl[b]);
    if (k == 0) atomicAdd(Z + u, zloc);
}

// Normalize + squash: s = S/Z ; mag_sq[b,k] = sum_u s^2 (reference quirk: sum
// over the num_units axis) ; v = mag_sq/(1+mag_sq) * s/mag.
__global__ void squash_k(const float* __restrict__ S, const float* __restrict__ Z,
                         float* __restrict__ vout)
{
    __shared__ float z_sh[UU];
    __shared__ float s2_sh[UK];
    __shared__ float mag_sh[KK];

    const int b = blockIdx.x;   // 32 blocks
    const int t = threadIdx.x;  // 512 = uk

    if (t < UU) z_sh[t] = Z[t];
    float ssum = S[b * UK + t];
    __syncthreads();

    float s = ssum / z_sh[t >> 4];
    s2_sh[t] = s * s;
    __syncthreads();

    if (t < KK) {
        float m = 0.f;
        for (int uu = 0; uu < UU; ++uu) m += s2_sh[uu * KK + t];
        mag_sh[t] = m;
    }
    __syncthreads();

    float msq = mag_sh[t & 15];
    float out = (msq / (1.0f + msq)) * s / sqrtf(msq);
    vout[b * UK + t] = out;
}

extern "C" void kernel_launch(void* const* d_in, const int* in_sizes, int n_in,
                              void* d_out, int out_size, void* d_ws, size_t ws_size,
                              hipStream_t stream)
{
    const float* x = (const float*)d_in[0];   // (B, IN, C)
    const float* W = (const float*)d_in[1];   // (C, U, K, IN)
    float* out = (float*)d_out;               // (B, U, K, 1) fp32

    char* ws = (char*)d_ws;

    // Workspace layout (main path). Zero-init region is contiguous [0, 0x140200):
    //   [0x000000, 0x030000)  S3  : 3 x 64KB  (S per pass -> no per-pass memset)
    //   [0x030000, 0x030180)  Z3  : 3 x 128B
    //   [0x030200, 0x040200)  vb  : 64KB
    //   [0x040200, 0x140200)  bio : 1MB
    //   [0x140400, ...     )  xT  : 16MB (fully written by transpose_x)
    const size_t XT_OFF = 0x140400;
    const size_t NEED   = XT_OFF + (size_t)CC * BB * INU * 4;

    if (ws_size >= NEED) {
        float* S3  = (float*)(ws);
        float* Z3  = (float*)(ws + 0x30000);
        float* vb  = (float*)(ws + 0x30200);
        float* bio = (float*)(ws + 0x40200);
        float* xT  = (float*)(ws + XT_OFF);

        hipMemsetAsync(ws, 0, 0x140200, stream);          // one memset for all state
        transpose_x<<<1024, 256, 0, stream>>>(x, xT);     // one-time, ~32MB of traffic

        for (int pass = 0; pass < 3; ++pass) {
            float* S = S3 + (size_t)pass * (BB * UK);
            float* Z =3 > 0 ? (Z3 + (size_t)pass * 32) : Z3;
            fused_pass<<<NBLK, 512, 0, stream>>>(W, xT, vb, bio, S, Z);
            float* vo = (pass == 2) ? out : vb;
            squash_k<<<BB, UK, 0, stream>>>(S, Z, vo);
        }
    } else {
        // Fallback: previous proven layout/kernels.
        float* S   = (float*)(ws);                         // 64 KB
        float* Z   = (float*)(ws + 65536);                 // 128 B (padded)
        float* vb  = (float*)(ws + 65536 + 256);           // 64 KB
        float* bio = (float*)(ws + 65536 + 256 + 65536);   // 1 MB

        hipMemsetAsync(vb,  0, BB * UK * 4, stream);
        hipMemsetAsync(bio, 0, CC * UU * 4, stream);

        for (int pass = 0; pass < 3; ++pass) {
            hipMemsetAsync(S, 0, BB * UK * 4, stream);
            hipMemsetAsync(Z, 0, UU * 4, stream);
            fused_pass_lds<<<256, 512, 0, stream>>>(x, W, vb, bio, S, Z);
            float* vo = (pass == 2) ? out : vb;
            squash_k<<<BB, UK, 0, stream>>>(S, Z, vo);
        }
    }
}

// Round 2
// 811.814 us; speedup vs baseline: 1.2390x; 1.2390x over previous
//
#include <hip/hip_runtime.h>

// Problem constants: B=32, IN=16, C=8192, U=32, K=16, 3 routing iters.
#define CC   8192
#define UU   32
#define KK   16
#define BB   32
#define INU  16
#define UK   512      // U*K
#define CPB  32       // channels per block
#define NBLK 256      // CC / CPB == CU count

typedef __attribute__((ext_vector_type(4))) float  f32x4;
typedef __attribute__((ext_vector_type(8))) __bf16 bf16x8;

// -------------------------------------------------------------------------
// One-time x transpose: xT[c][b*16+i] = x[b][i][c]  (proven in round 1).
// -------------------------------------------------------------------------
__global__ __launch_bounds__(256) void transpose_x(
    const float* __restrict__ x, float* __restrict__ xT)
{
    __shared__ float tile[64][65];
    const int bc = blockIdx.x & 127;           // 128 c-tiles of 64
    const int bb = blockIdx.x >> 7;            // 8 bi-tiles of 64 (B*IN = 512)
    const int c0 = bc * 64, bi0 = bb * 64;
    const int tx = threadIdx.x & 63, ty = threadIdx.x >> 6;  // 64 x 4
#pragma unroll
    for (int j = 0; j < 64; j += 4)
        tile[ty + j][tx] = x[(size_t)(bi0 + ty + j) * CC + (c0 + tx)];  // coalesced in c
    __syncthreads();
#pragma unroll
    for (int j = 0; j < 64; j += 4)                                      // coalesced in bi
        xT[(size_t)(c0 + ty + j) * (BB * INU) + (bi0 + tx)] = tile[tx][ty + j];
}

// -------------------------------------------------------------------------
// bf16 hi/lo split: w = hi + lo with |err| ~ 2^-17 |w|.
// -------------------------------------------------------------------------
__device__ inline void split4(f32x4 f, __bf16 h[4], __bf16 l[4])
{
#pragma unroll
    for (int i = 0; i < 4; ++i) {
        __bf16 hh = (__bf16)f[i];
        h[i] = hh;
        l[i] = (__bf16)(f[i] - (float)hh);
    }
}

__device__ inline bf16x8 pack8(const __bf16 a[4], const __bf16 b[4])
{
    bf16x8 r;
    r[0] = a[0]; r[1] = a[1]; r[2] = a[2]; r[3] = a[3];
    r[4] = b[0]; r[5] = b[1]; r[6] = b[2]; r[7] = b[3];
    return r;
}

// -------------------------------------------------------------------------
// MFMA routing pass. Per channel c:
//   u_hat[uk=512, b=32] = W_c[512,16] . x_c[16,32]   via bf16x3-split MFMA
//   a[u]   = (1/B) sum_{b,k} u_hat * v_in
//   b_new  = b_io + a ; e = exp(b_new) ; b_io <- b_new
//   Z[u]  += e ; S[b,uk] += e * u_hat
// 8 waves/block; wave w owns u = 4w..4w+3. A-tile (16k x 16i fp32) = 1KB is
// read as one permuted-coalesced dwordx4/lane and split to bf16 hi/lo in
// registers. Two 16x16x32 MFMAs produce hi*hi + lo*hi + hi*lo (K-halves map
// to operand-register halves). Zero LDS in the hot loop.
// Fragment maps (m89/m162): A row = lane&15, i = (lane>>4)*4 + j&3, half=j>>2;
// B col = lane&15, same i map; D col = lane&15 (b), row = (lane>>4)*4 + reg (k).
// -------------------------------------------------------------------------
__global__ __launch_bounds__(512, 2) void fused_mfma(
    const float* __restrict__ W, const float* __restrict__ xT,
    const float* __restrict__ v_in, float* __restrict__ b_io,
    float* __restrict__ S, float* __restrict__ Z)
{
    const int tid  = threadIdx.x;
    const int w    = tid >> 6;          // wave 0..7
    const int lane = tid & 63;
    const int col  = lane & 15;         // b within b-tile / k-row of A
    const int g    = lane >> 4;         // 0..3: i-quad selector
    const int c0   = blockIdx.x * CPB;
    const int u0   = w * 4;
    const int loff = col * 16 + g * 4;  // lane offset (floats) in a 1KB fp32 tile

    // v fragments + S accumulators, in the MFMA C/D layout.
    f32x4 vf[4][2], Sl[4][2];
#pragma unroll
    for (int uu = 0; uu < 4; ++uu)
#pragma unroll
        for (int bt = 0; bt < 2; ++bt) {
            const int b = bt * 16 + col;
#pragma unroll
            for (int r = 0; r < 4; ++r) {
                vf[uu][bt][r] = v_in[(size_t)b * UK + (u0 + uu) * KK + g * 4 + r];
                Sl[uu][bt][r] = 0.f;
            }
        }
    float zl[4] = {0.f, 0.f, 0.f, 0.f};

    // Prime c = c0 loads.
    f32x4 wf[4], xf[2], bio;
    {
        const float* wb = W + ((size_t)c0 * UU + u0) * (KK * INU) + loff;
#pragma unroll
        for (int uu = 0; uu < 4; ++uu) wf[uu] = *(const f32x4*)(wb + uu * 256);
        const float* xb = xT + (size_t)c0 * (BB * INU) + loff;
        xf[0] = *(const f32x4*)(xb);
        xf[1] = *(const f32x4*)(xb + 256);
        bio   = *(const f32x4*)(b_io + (size_t)c0 * UU + u0);
    }

    const __bf16 zb = (__bf16)0.f;
    const __bf16 z4[4] = {zb, zb, zb, zb};

    for (int cc = 0; cc < CPB; ++cc) {
        const int c = c0 + cc;
        const bool have_next = (cc + 1 < CPB);

        // Prefetch c+1 (W stream = the HBM traffic; x + b_io ride along).
        f32x4 wn[4], xn[2], bion;
        if (have_next) {
            const float* wb = W + ((size_t)(c + 1) * UU + u0) * (KK * INU) + loff;
#pragma unroll
            for (int uu = 0; uu < 4; ++uu) wn[uu] = *(const f32x4*)(wb + uu * 256);
            const float* xb = xT + (size_t)(c + 1) * (BB * INU) + loff;
            xn[0] = *(const f32x4*)(xb);
            xn[1] = *(const f32x4*)(xb + 256);
            bion  = *(const f32x4*)(b_io + (size_t)(c + 1) * UU + u0);
        }

        // x -> B operands (shared across the wave's 4 u-tiles).
        bf16x8 B1[2], B2[2];
#pragma unroll
        for (int bt = 0; bt < 2; ++bt) {
            __bf16 xh[4], xl[4];
            split4(xf[bt], xh, xl);
            B1[bt] = pack8(xh, xh);   // [xhi ; xhi]
            B2[bt] = pack8(xh, xl);   // [xhi ; xlo]
        }

        // W -> A operands, MFMA per (u, b-tile).
        f32x4 acc[4][2];
#pragma unroll
        for (int uu = 0; uu < 4; ++uu) {
            __bf16 wh[4], wl[4];
            split4(wf[uu], wh, wl);
            bf16x8 A1 = pack8(wh, wl);   // [Whi | Wlo]
            bf16x8 A2 = pack8(z4, wh);   // [ 0  | Whi]
#pragma unroll
            for (int bt = 0; bt < 2; ++bt) {
                f32x4 t = {0.f, 0.f, 0.f, 0.f};
                t = __builtin_amdgcn_mfma_f32_16x16x32_bf16(A1, B1[bt], t, 0, 0, 0); // hihi+lohi
                t = __builtin_amdgcn_mfma_f32_16x16x32_bf16(A2, B2[bt], t, 0, 0, 0); // + hilo
                acc[uu][bt] = t;
            }
        }

        // Agreement: p[u] = sum_{b,k} u_hat * v  (per-lane dot, then wave reduce).
        float p[4];
#pragma unroll
        for (int uu = 0; uu < 4; ++uu) {
            float d = 0.f;
#pragma unroll
            for (int bt = 0; bt < 2; ++bt)
#pragma unroll
                for (int r = 0; r < 4; ++r)
                    d = fmaf(acc[uu][bt][r], vf[uu][bt][r], d);
            p[uu] = d;
        }
#pragma unroll
        for (int off = 1; off < 64; off <<= 1) {
            p[0] += __shfl_xor(p[0], off);
            p[1] += __shfl_xor(p[1], off);
            p[2] += __shfl_xor(p[2], off);
            p[3] += __shfl_xor(p[3], off);
        }

        // Routing update (all lanes hold identical p after the reduce).
        f32x4 bnew;
        float e[4];
#pragma unroll
        for (int uu = 0; uu < 4; ++uu) {
            bnew[uu] = bio[uu] + p[uu] * (1.0f / (float)BB);
            e[uu]    = __expf(bnew[uu]);
            zl[uu]  += e[uu];
        }
        if (lane == 0) *(f32x4*)(b_io + (size_t)c * UU + u0) = bnew;

        // S accumulation: Sl += e[u] * u_hat  (register-resident, MFMA layout).
#pragma unroll
        for (int uu = 0; uu < 4; ++uu)
#pragma unroll
            for (int bt = 0; bt < 2; ++bt)
#pragma unroll
                for (int r = 0; r < 4; ++r)
                    Sl[uu][bt][r] = fmaf(e[uu], acc[uu][bt][r], Sl[uu][bt][r]);

        if (have_next) {
            wf[0] = wn[0]; wf[1] = wn[1]; wf[2] = wn[2]; wf[3] = wn[3];
            xf[0] = xn[0]; xf[1] = xn[1];
            bio   = bion;
        }
    }

    // Flush S (fragment-layout scatter; end-of-kernel only) and Z.
#pragma unroll
    for (int uu = 0; uu < 4; ++uu)
#pragma unroll
        for (int bt = 0; bt < 2; ++bt) {
            const int b = bt * 16 + col;
#pragma unroll
            for (int r = 0; r < 4; ++r)
                atomicAdd(S + (size_t)b * UK + (u0 + uu) * KK + g * 4 + r, Sl[uu][bt][r]);
        }
    if (lane == 0) {
#pragma unroll
        for (int uu = 0; uu < 4; ++uu) atomicAdd(Z + u0 + uu, zl[uu]);
    }
}

// -------------------------------------------------------------------------
// Fallback pass (proven 175us LDS-broadcast kernel) — only if ws too small.
// -------------------------------------------------------------------------
__global__ __launch_bounds__(512, 2) void fused_pass_lds(
    const float* __restrict__ x, const float* __restrict__ W,
    const float* __restrict__ v_in, float* __restrict__ b_io,
    float* __restrict__ S, float* __restrict__ Z)
{
    __shared__ float xs[16 * 516];

    const int t   = threadIdx.x;
    const int bid = blockIdx.x;
    const int c0  = bid * 32;
    const int u   = t >> 4;
    const int k   = t & 15;

    float v[BB], Sl[BB], uh[BB];
#pragma unroll
    for (int b = 0; b < BB; ++b) { v[b] = v_in[b * UK + t]; Sl[b] = 0.f; }
    float zloc = 0.f;

    float4 w0, w1, w2, w3;
    {
        const float4* p = (const float4*)(W + ((size_t)c0 * UK + t) * INU);
        w0 = p[0]; w1 = p[1]; w2 = p[2]; w3 = p[3];
    }

    for (int cc = 0; cc < 32; ++cc) {
        if ((cc & 15) == 0) {
            __syncthreads();
            const int cbase = c0 + (cc & ~15);
            for (int j = 0; j < 16; ++j) {
                int idx = j * 512 + t;
                int ccl = idx & 15;
                int bi  = idx >> 4;
                xs[ccl * 516 + bi] = x[bi * CC + cbase + ccl];
            }
            __syncthreads();
        }

        float4 n0, n1, n2, n3;
        const bool have_next = (cc + 1 < 32);
        if (have_next) {
            const float4* p = (const float4*)(W + ((size_t)(c0 + cc + 1) * UK + t) * INU);
            n0 = p[0]; n1 = p[1]; n2 = p[2]; n3 = p[3];
        }

        const float* xrow = &xs[(cc & 15) * 516];
        float ap = 0.f;
#pragma unroll
        for (int b = 0; b < BB; ++b) {
            const float4* xr = (const float4*)(xrow + b * INU);
            float4 x0 = xr[0], x1 = xr[1], x2 = xr[2], x3 = xr[3];
            float h;
            h = w0.x * x0.x;
            h = fmaf(w0.y, x0.y, h); h = fmaf(w0.z, x0.z, h); h = fmaf(w0.w, x0.w, h);
            h = fmaf(w1.x, x1.x, h); h = fmaf(w1.y, x1.y, h);
            h = fmaf(w1.z, x1.z, h); h = fmaf(w1.w, x1.w, h);
            h = fmaf(w2.x, x2.x, h); h = fmaf(w2.y, x2.y, h);
            h = fmaf(w2.z, x2.z, h); h = fmaf(w2.w, x2.w, h);
            h = fmaf(w3.x, x3.x, h); h = fmaf(w3.y, x3.y, h);
            h = fmaf(w3.z, x3.z, h); h = fmaf(w3.w, x3.w, h);
            uh[b] = h;
            ap = fmaf(h, v[b], ap);
        }

        ap += __shfl_xor(ap, 8);
        ap += __shfl_xor(ap, 4);
        ap += __shfl_xor(ap, 2);
        ap += __shfl_xor(ap, 1);

        const int c = c0 + cc;
        float bnew = b_io[c * UU + u] + ap * (1.0f / (float)BB);
        float e = __expf(bnew);
        zloc += e;
        if (k == 0) b_io[c * UU + u] = bnew;

#pragma unroll
        for (int b = 0; b < BB; ++b) Sl[b] = fmaf(e, uh[b], Sl[b]);

        if (have_next) { w0 = n0; w1 = n1; w2 = n2; w3 = n3; }
    }

#pragma unroll
    for (int b = 0; b < BB; ++b) atomicAdd(S + b * UK + t, Sl[b]);
    if (k == 0) atomicAdd(Z + u, zloc);
}

// Normalize + squash: s = S/Z ; mag_sq[b,k] = sum_u s^2 ; v = msq/(1+msq)*s/mag.
__global__ void squash_k(const float* __restrict__ S, const float* __restrict__ Z,
                         float* __restrict__ vout)
{
    __shared__ float z_sh[UU];
    __shared__ float s2_sh[UK];
    __shared__ float mag_sh[KK];

    const int b = blockIdx.x;   // 32 blocks
    const int t = threadIdx.x;  // 512 = uk

    if (t < UU) z_sh[t] = Z[t];
    float ssum = S[b * UK + t];
    __syncthreads();

    float s = ssum / z_sh[t >> 4];
    s2_sh[t] = s * s;
    __syncthreads();

    if (t < KK) {
        float m = 0.f;
        for (int uu = 0; uu < UU; ++uu) m += s2_sh[uu * KK + t];
        mag_sh[t] = m;
    }
    __syncthreads();

    float msq = mag_sh[t & 15];
    float out = (msq / (1.0f + msq)) * s / sqrtf(msq);
    vout[b * UK + t] = out;
}

extern "C" void kernel_launch(void* const* d_in, const int* in_sizes, int n_in,
                              void* d_out, int out_size, void* d_ws, size_t ws_size,
                              hipStream_t stream)
{
    const float* x = (const float*)d_in[0];   // (B, IN, C)
    const float* W = (const float*)d_in[1];   // (C, U, K, IN)
    float* out = (float*)d_out;               // (B, U, K, 1) fp32

    char* ws = (char*)d_ws;

    // Workspace layout. Zero-init region is contiguous [0, 0x140200):
    //   [0x000000, 0x030000)  S3  : 3 x 64KB  (per-pass S -> no per-pass memset)
    //   [0x030000, 0x030180)  Z3  : 3 x 128B
    //   [0x030200, 0x040200)  vb  : 64KB
    //   [0x040200, 0x140200)  bio : 1MB
    //   [0x140400, ...     )  xT  : 16MB (fully written by transpose_x)
    const size_t XT_OFF = 0x140400;
    const size_t NEED   = XT_OFF + (size_t)CC * BB * INU * 4;

    if (ws_size >= NEED) {
        float* S3  = (float*)(ws);
        float* Z3  = (float*)(ws + 0x30000);
        float* vb  = (float*)(ws + 0x30200);
        float* bio = (float*)(ws + 0x40200);
        float* xT  = (float*)(ws + XT_OFF);

        hipMemsetAsync(ws, 0, 0x140200, stream);          // one memset for all state
        transpose_x<<<1024, 256, 0, stream>>>(x, xT);     // one-time, ~32MB of traffic

        for (int pass = 0; pass < 3; ++pass) {
            float* S = S3 + (size_t)pass * (BB * UK);
            float* Z = Z3 + (size_t)pass * 32;
            fused_mfma<<<NBLK, 512, 0, stream>>>(W, xT, vb, bio, S, Z);
            float* vo = (pass == 2) ? out : vb;
            squash_k<<<BB, UK, 0, stream>>>(S, Z, vo);
        }
    } else {
        // Fallback: proven LDS-broadcast path.
        float* S   = (float*)(ws);                         // 64 KB
        float* Z   = (float*)(ws + 65536);                 // 128 B (padded)
        float* vb  = (float*)(ws + 65536 + 256);           // 64 KB
        float* bio = (float*)(ws + 65536 + 256 + 65536);   // 1 MB

        hipMemsetAsync(vb,  0, BB * UK * 4, stream);
        hipMemsetAsync(bio, 0, CC * UU * 4, stream);

        for (int pass = 0; pass < 3; ++pass) {
            hipMemsetAsync(S, 0, BB * UK * 4, stream);
            hipMemsetAsync(Z, 0, UU * 4, stream);
            fused_pass_lds<<<256, 512, 0, stream>>>(x, W, vb, bio, S, Z);
            float* vo = (pass == 2) ? out : vb;
            squash_k<<<BB, UK, 0, stream>>>(S, Z, vo);
        }
    }
}

// Round 3
// 772.673 us; speedup vs baseline: 1.3018x; 1.0507x over previous
//
#include <hip/hip_runtime.h>

// Problem constants: B=32, IN=16, C=8192, U=32, K=16, 3 routing iters.
#define CC   8192
#define UU   32
#define KK   16
#define BB   32
#define INU  16
#define UK   512      // U*K
#define CPB  32       // channels per c-group
#define NBLK 512      // (CC/CPB) c-groups x 2 u-halves

typedef __attribute__((ext_vector_type(4))) float  f32x4;
typedef __attribute__((ext_vector_type(8))) __bf16 bf16x8;

// -------------------------------------------------------------------------
// One-time x transpose: xT[c][b*16+i] = x[b][i][c]  (proven).
// -------------------------------------------------------------------------
__global__ __launch_bounds__(256) void transpose_x(
    const float* __restrict__ x, float* __restrict__ xT)
{
    __shared__ float tile[64][65];
    const int bc = blockIdx.x & 127;           // 128 c-tiles of 64
    const int bb = blockIdx.x >> 7;            // 8 bi-tiles of 64 (B*IN = 512)
    const int c0 = bc * 64, bi0 = bb * 64;
    const int tx = threadIdx.x & 63, ty = threadIdx.x >> 6;  // 64 x 4
#pragma unroll
    for (int j = 0; j < 64; j += 4)
        tile[ty + j][tx] = x[(size_t)(bi0 + ty + j) * CC + (c0 + tx)];  // coalesced in c
    __syncthreads();
#pragma unroll
    for (int j = 0; j < 64; j += 4)                                      // coalesced in bi
        xT[(size_t)(c0 + ty + j) * (BB * INU) + (bi0 + tx)] = tile[tx][ty + j];
}

// -------------------------------------------------------------------------
// bf16 hi/lo split: w = hi + lo with |err| ~ 2^-17 |w|.
// -------------------------------------------------------------------------
__device__ inline void split4(f32x4 f, __bf16 h[4], __bf16 l[4])
{
#pragma unroll
    for (int i = 0; i < 4; ++i) {
        __bf16 hh = (__bf16)f[i];
        h[i] = hh;
        l[i] = (__bf16)(f[i] - (float)hh);
    }
}

__device__ inline bf16x8 pack8(const __bf16 a[4], const __bf16 b[4])
{
    bf16x8 r;
    r[0] = a[0]; r[1] = a[1]; r[2] = a[2]; r[3] = a[3];
    r[4] = b[0]; r[5] = b[1]; r[6] = b[2]; r[7] = b[3];
    return r;
}

// -------------------------------------------------------------------------
// MFMA routing pass, u-split: block = (c-group, u-half); wave owns 2 u.
// Per channel c, per u: u_hat[16k x 32b] = W_cu[16,16] . x_c[16,32] via
// bf16x3-split MFMA: A=[wh|wl]; B1=[xh;xh] -> wh.xh+wl.xh; B2=[xl;0] -> wh.xl.
// Then a = (1/B) sum u_hat*v ; bnew = bio + a ; e = exp ; Z += e ; Sl += e*u_hat.
// Zero LDS; ~122 VGPR -> 2 blocks/CU (4 waves/SIMD) with no spills.
// Fragment maps (verified by round-2 pass): A row=lane&15 (caps-k),
// contraction i = (lane>>4)*4 + (j&3), half = j>>2; B col=lane&15 (b), same i
// map; D col=lane&15 (b), row = (lane>>4)*4 + reg (caps-k).
// -------------------------------------------------------------------------
__global__ __launch_bounds__(512, 4) void fused_mfma(
    const float* __restrict__ W, const float* __restrict__ xT,
    const float* __restrict__ v_in, float* __restrict__ b_io,
    float* __restrict__ S, float* __restrict__ Z)
{
    const int tid  = threadIdx.x;
    const int w    = tid >> 6;                 // wave 0..7
    const int lane = tid & 63;
    const int col  = lane & 15;                // b within b-tile / caps-k row of A
    const int g    = lane >> 4;                // i-quad selector
    const int c0   = (blockIdx.x >> 1) * CPB;  // c-group
    const int u0   = (blockIdx.x & 1) * 16 + w * 2;  // u-half + wave -> 2 u
    const int loff = col * 16 + g * 4;         // lane offset (floats) in a 1KB tile

    // Persistent per-wave state (MFMA C/D layout).
    f32x4 vf[2][2], Sl[2][2];
#pragma unroll
    for (int uu = 0; uu < 2; ++uu)
#pragma unroll
        for (int bt = 0; bt < 2; ++bt) {
            const int b = bt * 16 + col;
#pragma unroll
            for (int r = 0; r < 4; ++r) {
                vf[uu][bt][r] = v_in[(size_t)b * UK + (u0 + uu) * KK + g * 4 + r];
                Sl[uu][bt][r] = 0.f;
            }
        }
    float zl0 = 0.f, zl1 = 0.f;

    const __bf16 zb = (__bf16)0.f;
    const __bf16 z4[4] = {zb, zb, zb, zb};

    // Prime c = c0.
    f32x4 wf[2], xf[2];
    {
        const float* wb = W + ((size_t)c0 * UU + u0) * (KK * INU) + loff;
        wf[0] = *(const f32x4*)(wb);
        wf[1] = *(const f32x4*)(wb + 256);
        const float* xb = xT + (size_t)c0 * (BB * INU) + loff;
        xf[0] = *(const f32x4*)(xb);
        xf[1] = *(const f32x4*)(xb + 256);
    }

    for (int cc = 0; cc < CPB; ++cc) {
        const int c = c0 + cc;
        const bool have_next = (cc + 1 < CPB);

        // b_io for this channel: 8B broadcast, L2-resident; consumed only after
        // the MFMA+reduce chain -> latency self-hiding, no prefetch regs needed.
        float2 bv = *(const float2*)(b_io + (size_t)c * UU + u0);

        // Prefetch c+1 (W = the HBM stream; x rides along).
        f32x4 wn[2], xn[2];
        if (have_next) {
            const float* wb = W + ((size_t)(c + 1) * UU + u0) * (KK * INU) + loff;
            wn[0] = *(const f32x4*)(wb);
            wn[1] = *(const f32x4*)(wb + 256);
            const float* xb = xT + (size_t)(c + 1) * (BB * INU) + loff;
            xn[0] = *(const f32x4*)(xb);
            xn[1] = *(const f32x4*)(xb + 256);
        }

        // x -> B operands (shared by both u-tiles).
        bf16x8 B1[2], B2[2];
#pragma unroll
        for (int bt = 0; bt < 2; ++bt) {
            __bf16 xh[4], xl[4];
            split4(xf[bt], xh, xl);
            B1[bt] = pack8(xh, xh);   // [xhi ; xhi]
            B2[bt] = pack8(xl, z4);   // [xlo ;  0 ]
        }

        // MFMAs: one shared A per u.
        f32x4 acc[2][2];
#pragma unroll
        for (int uu = 0; uu < 2; ++uu) {
            __bf16 wh[4], wl[4];
            split4(wf[uu], wh, wl);
            bf16x8 A = pack8(wh, wl); // [Whi | Wlo]
#pragma unroll
            for (int bt = 0; bt < 2; ++bt) {
                f32x4 t = {0.f, 0.f, 0.f, 0.f};
                t = __builtin_amdgcn_mfma_f32_16x16x32_bf16(A, B1[bt], t, 0, 0, 0); // hihi+lohi
                t = __builtin_amdgcn_mfma_f32_16x16x32_bf16(A, B2[bt], t, 0, 0, 0); // + hilo
                acc[uu][bt] = t;
            }
        }

        // Agreement: per-lane dot, then full-wave reduce (covers all b,k).
        float p0 = 0.f, p1 = 0.f;
#pragma unroll
        for (int bt = 0; bt < 2; ++bt)
#pragma unroll
            for (int r = 0; r < 4; ++r) {
                p0 = fmaf(acc[0][bt][r], vf[0][bt][r], p0);
                p1 = fmaf(acc[1][bt][r], vf[1][bt][r], p1);
            }
#pragma unroll
        for (int off = 1; off < 64; off <<= 1) {
            p0 += __shfl_xor(p0, off);
            p1 += __shfl_xor(p1, off);
        }

        // Routing update (identical on all lanes post-reduce).
        const float bn0 = bv.x + p0 * (1.0f / (float)BB);
        const float bn1 = bv.y + p1 * (1.0f / (float)BB);
        const float e0 = __expf(bn0);
        const float e1 = __expf(bn1);
        zl0 += e0; zl1 += e1;
        if (lane == 0) *(float2*)(b_io + (size_t)c * UU + u0) = make_float2(bn0, bn1);

        // S accumulation in registers (MFMA layout).
#pragma unroll
        for (int bt = 0; bt < 2; ++bt)
#pragma unroll
            for (int r = 0; r < 4; ++r) {
                Sl[0][bt][r] = fmaf(e0, acc[0][bt][r], Sl[0][bt][r]);
                Sl[1][bt][r] = fmaf(e1, acc[1][bt][r], Sl[1][bt][r]);
            }

        if (have_next) {
            wf[0] = wn[0]; wf[1] = wn[1];
            xf[0] = xn[0]; xf[1] = xn[1];
        }
    }

    // Flush S (fragment-layout scatter, end-of-kernel only) and Z.
#pragma unroll
    for (int uu = 0; uu < 2; ++uu)
#pragma unroll
        for (int bt = 0; bt < 2; ++bt) {
            const int b = bt * 16 + col;
#pragma unroll
            for (int r = 0; r < 4; ++r)
                atomicAdd(S + (size_t)b * UK + (u0 + uu) * KK + g * 4 + r, Sl[uu][bt][r]);
        }
    if (lane == 0) {
        atomicAdd(Z + u0,     zl0);
        atomicAdd(Z + u0 + 1, zl1);
    }
}

// -------------------------------------------------------------------------
// Fallback pass (proven 175us LDS-broadcast kernel) — only if ws too small.
// -------------------------------------------------------------------------
__global__ __launch_bounds__(512, 2) void fused_pass_lds(
    const float* __restrict__ x, const float* __restrict__ W,
    const float* __restrict__ v_in, float* __restrict__ b_io,
    float* __restrict__ S, float* __restrict__ Z)
{
    __shared__ float xs[16 * 516];

    const int t   = threadIdx.x;
    const int bid = blockIdx.x;
    const int c0  = bid * 32;
    const int u   = t >> 4;
    const int k   = t & 15;

    float v[BB], Sl[BB], uh[BB];
#pragma unroll
    for (int b = 0; b < BB; ++b) { v[b] = v_in[b * UK + t]; Sl[b] = 0.f; }
    float zloc = 0.f;

    float4 w0, w1, w2, w3;
    {
        const float4* p = (const float4*)(W + ((size_t)c0 * UK + t) * INU);
        w0 = p[0]; w1 = p[1]; w2 = p[2]; w3 = p[3];
    }

    for (int cc = 0; cc < 32; ++cc) {
        if ((cc & 15) == 0) {
            __syncthreads();
            const int cbase = c0 + (cc & ~15);
            for (int j = 0; j < 16; ++j) {
                int idx = j * 512 + t;
                int ccl = idx & 15;
                int bi  = idx >> 4;
                xs[ccl * 516 + bi] = x[bi * CC + cbase + ccl];
            }
            __syncthreads();
        }

        float4 n0, n1, n2, n3;
        const bool have_next = (cc + 1 < 32);
        if (have_next) {
            const float4* p = (const float4*)(W + ((size_t)(c0 + cc + 1) * UK + t) * INU);
            n0 = p[0]; n1 = p[1]; n2 = p[2]; n3 = p[3];
        }

        const float* xrow = &xs[(cc & 15) * 516];
        float ap = 0.f;
#pragma unroll
        for (int b = 0; b < BB; ++b) {
            const float4* xr = (const float4*)(xrow + b * INU);
            float4 x0 = xr[0], x1 = xr[1], x2 = xr[2], x3 = xr[3];
            float h;
            h = w0.x * x0.x;
            h = fmaf(w0.y, x0.y, h); h = fmaf(w0.z, x0.z, h); h = fmaf(w0.w, x0.w, h);
            h = fmaf(w1.x, x1.x, h); h = fmaf(w1.y, x1.y, h);
            h = fmaf(w1.z, x1.z, h); h = fmaf(w1.w, x1.w, h);
            h = fmaf(w2.x, x2.x, h); h = fmaf(w2.y, x2.y, h);
            h = fmaf(w2.z, x2.z, h); h = fmaf(w2.w, x2.w, h);
            h = fmaf(w3.x, x3.x, h); h = fmaf(w3.y, x3.y, h);
            h = fmaf(w3.z, x3.z, h); h = fmaf(w3.w, x3.w, h);
            uh[b] = h;
            ap = fmaf(h, v[b], ap);
        }

        ap += __shfl_xor(ap, 8);
        ap += __shfl_xor(ap, 4);
        ap += __shfl_xor(ap, 2);
        ap += __shfl_xor(ap, 1);

        const int c = c0 + cc;
        float bnew = b_io[c * UU + u] + ap * (1.0f / (float)BB);
        float e = __expf(bnew);
        zloc += e;
        if (k == 0) b_io[c * UU + u] = bnew;

#pragma unroll
        for (int b = 0; b < BB; ++b) Sl[b] = fmaf(e, uh[b], Sl[b]);

        if (have_next) { w0 = n0; w1 = n1; w2 = n2; w3 = n3; }
    }

#pragma unroll
    for (int b = 0; b < BB; ++b) atomicAdd(S + b * UK + t, Sl[b]);
    if (k == 0) atomicAdd(Z + u, zloc);
}

// Normalize + squash: s = S/Z ; mag_sq[b,k] = sum_u s^2 ; v = msq/(1+msq)*s/mag.
__global__ void squash_k(const float* __restrict__ S, const float* __restrict__ Z,
                         float* __restrict__ vout)
{
    __shared__ float z_sh[UU];
    __shared__ float s2_sh[UK];
    __shared__ float mag_sh[KK];

    const int b = blockIdx.x;   // 32 blocks
    const int t = threadIdx.x;  // 512 = uk

    if (t < UU) z_sh[t] = Z[t];
    float ssum = S[b * UK + t];
    __syncthreads();

    float s = ssum / z_sh[t >> 4];
    s2_sh[t] = s * s;
    __syncthreads();

    if (t < KK) {
        float m = 0.f;
        for (int uu = 0; uu < UU; ++uu) m += s2_sh[uu * KK + t];
        mag_sh[t] = m;
    }
    __syncthreads();

    float msq = mag_sh[t & 15];
    float out = (msq / (1.0f + msq)) * s / sqrtf(msq);
    vout[b * UK + t] = out;
}

extern "C" void kernel_launch(void* const* d_in, const int* in_sizes, int n_in,
                              void* d_out, int out_size, void* d_ws, size_t ws_size,
                              hipStream_t stream)
{
    const float* x = (const float*)d_in[0];   // (B, IN, C)
    const float* W = (const float*)d_in[1];   // (C, U, K, IN)
    float* out = (float*)d_out;               // (B, U, K, 1) fp32

    char* ws = (char*)d_ws;

    // Workspace layout. Zero-init region is contiguous [0, 0x140200):
    //   [0x000000, 0x030000)  S3  : 3 x 64KB  (per-pass S -> no per-pass memset)
    //   [0x030000, 0x030180)  Z3  : 3 x 128B
    //   [0x030200, 0x040200)  vb  : 64KB
    //   [0x040200, 0x140200)  bio : 1MB
    //   [0x140400, ...     )  xT  : 16MB (fully written by transpose_x)
    const size_t XT_OFF = 0x140400;
    const size_t NEED   = XT_OFF + (size_t)CC * BB * INU * 4;

    if (ws_size >= NEED) {
        float* S3  = (float*)(ws);
        float* Z3  = (float*)(ws + 0x30000);
        float* vb  = (float*)(ws + 0x30200);
        float* bio = (float*)(ws + 0x40200);
        float* xT  = (float*)(ws + XT_OFF);

        hipMemsetAsync(ws, 0, 0x140200, stream);          // one memset for all state
        transpose_x<<<1024, 256, 0, stream>>>(x, xT);     // one-time, ~32MB of traffic

        for (int pass = 0; pass < 3; ++pass) {
            float* S = S3 + (size_t)pass * (BB * UK);
            float* Z = Z3 + (size_t)pass * 32;
            fused_mfma<<<NBLK, 512, 0, stream>>>(W, xT, vb, bio, S, Z);
            float* vo = (pass == 2) ? out : vb;
            squash_k<<<BB, UK, 0, stream>>>(S, Z, vo);
        }
    } else {
        // Fallback: proven LDS-broadcast path.
        float* S   = (float*)(ws);                         // 64 KB
        float* Z   = (float*)(ws + 65536);                 // 128 B (padded)
        float* vb  = (float*)(ws + 65536 + 256);           // 64 KB
        float* bio = (float*)(ws + 65536 + 256 + 65536);   // 1 MB

        hipMemsetAsync(vb,  0, BB * UK * 4, stream);
        hipMemsetAsync(bio, 0, CC * UU * 4, stream);

        for (int pass = 0; pass < 3; ++pass) {
            hipMemsetAsync(S, 0, BB * UK * 4, stream);
            hipMemsetAsync(Z, 0, UU * 4, stream);
            fused_pass_lds<<<256, 512, 0, stream>>>(x, W, vb, bio, S, Z);
            float* vo = (pass == 2) ? out : vb;
            squash_k<<<BB, UK, 0, stream>>>(S, Z, vo);
        }
    }
}